// Round 6
// baseline (321.350 us; speedup 1.0000x reference)
//
#include <hip/hip_runtime.h>

// FastAttention (Performer linear attention), B=4 H=8 N=4096 D=F=64, fp32.
// SINGLE kernel, 1024 blocks x 256 threads, 32 blocks/head (128 rows each).
// Producer-consumer inside one launch via per-block release flags:
//   phase A: bfrag = bf16(proj*log2e), column-permuted so MFMA tile ft
//            computes feature f = fp*4+ft (fp=lane&15) -> V/out/stats dwordx4.
//   phase B: k' = exp2(k @ bfrag); block-private partial (ksum[64]||ctx[64])
//            -> ws[bid*128..]; Q loads issued here to overlap.
//   release: __syncthreads (each wave drains stores) + tid0 agent-scope
//            release-store flags[bid]=MAGIC (wbl2 -> partials visible in L3).
//   acquire: lanes 0..31 spin on this head's 32 flags (agent-scope acquire,
//            L2-bypass); __threadfence (buffer_inv) -> plain loads fresh.
//   phase C: reduce head's 32 partials (L3-served, 16 KB).
//   phase D: q' = exp2(q @ bfrag); denom = q'.(ksum+1e-6); out = q'*ctx/denom.
// Deadlock safety WITHOUT full-grid residency: a block waits only on its own
// head's 32 blocks, contiguous in bid/dispatch order -> any >=32-block
// residency progresses head-by-head (no grid-wide sync anywhere).
// Flags need no init: ws is poisoned 0xAA (!= MAGIC); one write per flag/call.
// ws: [0 .. 128K) floats = partials; flags = 1024 ints after that.

#define NHEADS 32
#define SEQ    4096
#define DDIM   64
#define LOG2E  1.44269504088896341f
#define MAGIC  0x13579BDF

typedef __attribute__((ext_vector_type(8))) short short8;
typedef __attribute__((ext_vector_type(4))) float floatx4;
typedef __attribute__((ext_vector_type(2))) float floatx2;

__device__ __forceinline__ short f2bf(float x) {
    unsigned int u = __float_as_uint(x);
    u += 0x7fffu + ((u >> 16) & 1u);
    return (short)(u >> 16);
}

__device__ __forceinline__ short8 load8_bf16(const float* __restrict__ p) {
    floatx4 a = *(const floatx4*)p;
    floatx4 b = *(const floatx4*)(p + 4);
    short8 t;
    t[0] = f2bf(a[0]); t[1] = f2bf(a[1]); t[2] = f2bf(a[2]); t[3] = f2bf(a[3]);
    t[4] = f2bf(b[0]); t[5] = f2bf(b[1]); t[6] = f2bf(b[2]); t[7] = f2bf(b[3]);
    return t;
}

__device__ __forceinline__ short8 load8_bf16_scale(const float* __restrict__ p, float s) {
    floatx4 a = *(const floatx4*)p;
    floatx4 b = *(const floatx4*)(p + 4);
    short8 t;
    t[0] = f2bf(a[0] * s); t[1] = f2bf(a[1] * s); t[2] = f2bf(a[2] * s); t[3] = f2bf(a[3] * s);
    t[4] = f2bf(b[0] * s); t[5] = f2bf(b[1] * s); t[6] = f2bf(b[2] * s); t[7] = f2bf(b[3] * s);
    return t;
}

__global__ __launch_bounds__(256, 4) void fa_fused(const float* __restrict__ Q,
                                                   const float* __restrict__ K,
                                                   const float* __restrict__ V,
                                                   const float* __restrict__ proj,
                                                   float* __restrict__ ws,
                                                   int* __restrict__ flags,
                                                   float* __restrict__ out) {
    const int bid  = blockIdx.x;
    const int head = bid >> 5;          // 32 heads x 32 segments of 128 rows
    const int seg  = bid & 31;
    const int tid  = threadIdx.x;
    const int w    = tid >> 6;
    const int lane = tid & 63;
    const int fp   = lane & 15;
    const int g    = lane >> 4;
    const long hbase = (long)head * SEQ;

    // ---- phase A: proj -> bf16 B-fragments (scaled by log2e), f = fp*4+ft
    short8 bfrag[4][2];
#pragma unroll
    for (int ft = 0; ft < 4; ++ft)
#pragma unroll
        for (int half = 0; half < 2; ++half)
            bfrag[ft][half] =
                load8_bf16_scale(proj + (fp * 4 + ft) * DDIM + half * 32 + g * 8, LOG2E);

    // ---- phase B: K/V streaming (128 rows)
    float ksum[4] = {0.f, 0.f, 0.f, 0.f};
    float ctx[4]  = {0.f, 0.f, 0.f, 0.f};
#pragma unroll
    for (int it = 0; it < 2; ++it) {
        const int row0 = seg * 128 + it * 64 + w * 16;
        const float* ap = K + (hbase + row0 + fp) * DDIM;
        short8 a0 = load8_bf16(ap + g * 8);
        short8 a1 = load8_bf16(ap + 32 + g * 8);

        floatx4 acc[4];
#pragma unroll
        for (int ft = 0; ft < 4; ++ft) {
            floatx4 z = {0.f, 0.f, 0.f, 0.f};
            z = __builtin_amdgcn_mfma_f32_16x16x32_bf16(a0, bfrag[ft][0], z, 0, 0, 0);
            z = __builtin_amdgcn_mfma_f32_16x16x32_bf16(a1, bfrag[ft][1], z, 0, 0, 0);
            acc[ft] = z;
        }
        // C layout: col f = fp*4+ft, row = row0 + g*4 + r
#pragma unroll
        for (int r = 0; r < 4; ++r) {
            const floatx4 vv =
                *(const floatx4*)(V + (hbase + row0 + g * 4 + r) * DDIM + fp * 4);
#pragma unroll
            for (int ft = 0; ft < 4; ++ft) {
                float kp = __builtin_amdgcn_exp2f(acc[ft][r]);
                ksum[ft] += kp;
                ctx[ft]  += kp * vv[ft];
            }
        }
    }

    // ---- Q prefetch + convert (overlaps the reduction/flag phases below)
    short8 qfrag[2][2];
#pragma unroll
    for (int it = 0; it < 2; ++it) {
        const float* qp_ = Q + (hbase + seg * 128 + it * 64 + w * 16 + fp) * DDIM;
        qfrag[it][0] = load8_bf16(qp_ + g * 8);
        qfrag[it][1] = load8_bf16(qp_ + 32 + g * 8);
    }

    // ---- block-level reduce -> private partial in ws
#pragma unroll
    for (int ft = 0; ft < 4; ++ft) {
        ksum[ft] += __shfl_xor(ksum[ft], 16); ksum[ft] += __shfl_xor(ksum[ft], 32);
        ctx[ft]  += __shfl_xor(ctx[ft], 16);  ctx[ft]  += __shfl_xor(ctx[ft], 32);
    }
    __shared__ float smem[4][128];
    if (lane < 16) {
#pragma unroll
        for (int ft = 0; ft < 4; ++ft) {
            smem[w][fp * 4 + ft]      = ksum[ft];
            smem[w][64 + fp * 4 + ft] = ctx[ft];
        }
    }
    __syncthreads();
    if (tid < 128)
        ws[bid * 128 + tid] = smem[0][tid] + smem[1][tid] + smem[2][tid] + smem[3][tid];

    // ---- release: drain all waves' stores, then publish flag (agent scope)
    __syncthreads();   // each wave executes s_waitcnt vmcnt(0) before barrier
    if (tid == 0)
        __hip_atomic_store(&flags[bid], MAGIC, __ATOMIC_RELEASE,
                           __HIP_MEMORY_SCOPE_AGENT);

    // ---- acquire: wait for this head's 32 partials
    if (tid < 32) {
        while (__hip_atomic_load(&flags[head * 32 + tid], __ATOMIC_ACQUIRE,
                                 __HIP_MEMORY_SCOPE_AGENT) != MAGIC)
            __builtin_amdgcn_s_sleep(1);
    }
    __syncthreads();
    __threadfence();   // invalidate caches so plain partial loads are fresh

    // ---- phase C: reduce this head's 32 partials (wave w: partials 8w..8w+7)
    floatx2 acc2 = {0.f, 0.f};
#pragma unroll
    for (int p = 0; p < 8; ++p) {
        floatx2 t = *(const floatx2*)(ws + (long)(head * 32 + w * 8 + p) * 128 + lane * 2);
        acc2[0] += t[0];
        acc2[1] += t[1];
    }
    __syncthreads();   // smem reuse barrier
    smem[w][lane * 2]     = acc2[0];
    smem[w][lane * 2 + 1] = acc2[1];
    __syncthreads();
    if (tid < 128)
        smem[0][tid] = smem[0][tid] + smem[1][tid] + smem[2][tid] + smem[3][tid];
    __syncthreads();
    floatx4 ksr  = *(const floatx4*)(&smem[0][fp * 4]);
    floatx4 ctxr = *(const floatx4*)(&smem[0][64 + fp * 4]);
#pragma unroll
    for (int ft = 0; ft < 4; ++ft) ksr[ft] += 1e-6f;

    // ---- phase D: Q feature map + normalize + store
#pragma unroll
    for (int it = 0; it < 2; ++it) {
        const int row0 = seg * 128 + it * 64 + w * 16;
        float qp[4][4];
        float denom[4] = {0.f, 0.f, 0.f, 0.f};
#pragma unroll
        for (int ft = 0; ft < 4; ++ft) {
            floatx4 z = {0.f, 0.f, 0.f, 0.f};
            z = __builtin_amdgcn_mfma_f32_16x16x32_bf16(qfrag[it][0], bfrag[ft][0], z, 0, 0, 0);
            z = __builtin_amdgcn_mfma_f32_16x16x32_bf16(qfrag[it][1], bfrag[ft][1], z, 0, 0, 0);
#pragma unroll
            for (int r = 0; r < 4; ++r) {
                float e = __builtin_amdgcn_exp2f(z[r]);
                qp[ft][r] = e;
                denom[r] += e * ksr[ft];
            }
        }
#pragma unroll
        for (int r = 0; r < 4; ++r) {
            denom[r] += __shfl_xor(denom[r], 1);
            denom[r] += __shfl_xor(denom[r], 2);
            denom[r] += __shfl_xor(denom[r], 4);
            denom[r] += __shfl_xor(denom[r], 8);
            denom[r] = 1.0f / denom[r];
        }
#pragma unroll
        for (int r = 0; r < 4; ++r) {
            floatx4 o;
#pragma unroll
            for (int ft = 0; ft < 4; ++ft)
                o[ft] = qp[ft][r] * ctxr[ft] * denom[r];
            *(floatx4*)(out + (hbase + row0 + g * 4 + r) * DDIM + fp * 4) = o;
        }
    }
}

extern "C" void kernel_launch(void* const* d_in, const int* in_sizes, int n_in,
                              void* d_out, int out_size, void* d_ws, size_t ws_size,
                              hipStream_t stream) {
    const float* q    = (const float*)d_in[0];
    const float* k    = (const float*)d_in[1];
    const float* v    = (const float*)d_in[2];
    const float* proj = (const float*)d_in[3];
    float* out = (float*)d_out;
    float* ws  = (float*)d_ws;                     // 1024*128 floats partials
    int*   flags = (int*)(ws + 1024 * 128);        // 1024 flags (poison != MAGIC)

    fa_fused<<<NHEADS * 32, 256, 0, stream>>>(q, k, v, proj, ws, flags, out);
}

// Round 7
// 136.335 us; speedup vs baseline: 2.3571x; 2.3571x over previous
//
#include <hip/hip_runtime.h>

// FastAttention (Performer linear attention), B=4 H=8 N=4096 D=F=64, fp32.
// Round-3 champion structure (prep + pass1 + pass2) with latency fixes:
//   prep : zero per-head accumulators; build proj*log2(e) bf16 fragment table
//   pass1: ALL K/V raw loads issued first (16 dwordx4/lane in flight), then
//          convert+MFMA: k' = exp2(k @ proj'); atomicAdd partials -> ws
//   pass2: Q raw loads issued FIRST (HBM), then L2-hot table/stats; out =
//          q'*ctx/(q'.(ksum+1e-6))
// Column permutation: MFMA tile ft computes feature f = fp*4+ft (fp=lane&15),
// so V loads, stats and out stores are all dwordx4.
// ws: [0..4096) floats = 32 heads x (ksum[64]||ctx[64]); then 4096-short table
//     table index: (ft*2+half)*512 + lane*8 + j ; value bf16(proj[f][d]*log2e)

#define NHEADS 32
#define SEQ    4096
#define DDIM   64
#define ACC_FLOATS (NHEADS * 128)
#define LOG2E 1.44269504088896341f

typedef __attribute__((ext_vector_type(8))) short short8;
typedef __attribute__((ext_vector_type(4))) float floatx4;

__device__ __forceinline__ short f2bf(float x) {
    unsigned int u = __float_as_uint(x);
    u += 0x7fffu + ((u >> 16) & 1u);
    return (short)(u >> 16);
}

__device__ __forceinline__ short8 cvt8(floatx4 a, floatx4 b) {
    short8 t;
    t[0] = f2bf(a[0]); t[1] = f2bf(a[1]); t[2] = f2bf(a[2]); t[3] = f2bf(a[3]);
    t[4] = f2bf(b[0]); t[5] = f2bf(b[1]); t[6] = f2bf(b[2]); t[7] = f2bf(b[3]);
    return t;
}

__device__ __forceinline__ void load_bfrag_ws(const short* __restrict__ pbf,
                                              int lane, short8 bfrag[4][2]) {
#pragma unroll
    for (int ft = 0; ft < 4; ++ft)
#pragma unroll
        for (int half = 0; half < 2; ++half)
            bfrag[ft][half] = *(const short8*)(pbf + (ft * 2 + half) * 512 + lane * 8);
}

// blocks 0..31: zero accumulators. block 32: build proj bf16 fragment table.
__global__ __launch_bounds__(128) void fa_prep(const float* __restrict__ proj,
                                               float* __restrict__ ws) {
    const int tid = threadIdx.x;
    if (blockIdx.x < 32) {
        ws[blockIdx.x * 128 + tid] = 0.0f;
        return;
    }
    short* pbf = (short*)(ws + ACC_FLOATS);
#pragma unroll
    for (int i = 0; i < 32; ++i) {
        int idx  = tid * 32 + i;          // 0..4095
        int ft2h = idx >> 9;              // (ft*2+half)
        int rem  = idx & 511;
        int lane = rem >> 3;
        int j    = rem & 7;
        int ft   = ft2h >> 1;
        int half = ft2h & 1;
        int fp   = lane & 15;
        int g    = lane >> 4;
        pbf[idx] = f2bf(proj[(fp * 4 + ft) * DDIM + half * 32 + g * 8 + j] * LOG2E);
    }
}

__global__ __launch_bounds__(256, 4) void fa_pass1(const float* __restrict__ K,
                                                   const float* __restrict__ V,
                                                   float* __restrict__ ws) {
    const int head = blockIdx.x >> 5;   // 32 heads x 32 segments of 128 rows
    const int seg  = blockIdx.x & 31;
    const int tid  = threadIdx.x;
    const int w    = tid >> 6;
    const int lane = tid & 63;
    const int fp   = lane & 15;
    const int g    = lane >> 4;
    const long hbase = (long)head * SEQ;
    const int rowb = seg * 128 + w * 16;

    // ---- issue ALL raw global loads first (16 dwordx4 per lane in flight)
    floatx4 kraw[2][4];
#pragma unroll
    for (int it = 0; it < 2; ++it) {
        const float* ap = K + (hbase + rowb + it * 64 + fp) * DDIM;
        kraw[it][0] = *(const floatx4*)(ap + g * 8);
        kraw[it][1] = *(const floatx4*)(ap + g * 8 + 4);
        kraw[it][2] = *(const floatx4*)(ap + 32 + g * 8);
        kraw[it][3] = *(const floatx4*)(ap + 32 + g * 8 + 4);
    }
    floatx4 vraw[2][4];
#pragma unroll
    for (int it = 0; it < 2; ++it)
#pragma unroll
        for (int r = 0; r < 4; ++r)
            vraw[it][r] =
                *(const floatx4*)(V + (hbase + rowb + it * 64 + g * 4 + r) * DDIM + fp * 4);

    // L2-hot fragment table (lgkm-independent of the above)
    const short* pbf = (const short*)(ws + ACC_FLOATS);
    short8 bfrag[4][2];
    load_bfrag_ws(pbf, lane, bfrag);

    float ksum[4] = {0.f, 0.f, 0.f, 0.f};
    float ctx[4]  = {0.f, 0.f, 0.f, 0.f};

#pragma unroll
    for (int it = 0; it < 2; ++it) {
        short8 a0 = cvt8(kraw[it][0], kraw[it][1]);
        short8 a1 = cvt8(kraw[it][2], kraw[it][3]);

        floatx4 acc[4];
#pragma unroll
        for (int ft = 0; ft < 4; ++ft) {
            floatx4 z = {0.f, 0.f, 0.f, 0.f};
            z = __builtin_amdgcn_mfma_f32_16x16x32_bf16(a0, bfrag[ft][0], z, 0, 0, 0);
            z = __builtin_amdgcn_mfma_f32_16x16x32_bf16(a1, bfrag[ft][1], z, 0, 0, 0);
            acc[ft] = z;
        }
        // C layout: col f = fp*4+ft, row = rowb + it*64 + g*4 + r
#pragma unroll
        for (int r = 0; r < 4; ++r) {
#pragma unroll
            for (int ft = 0; ft < 4; ++ft) {
                float kp = __builtin_amdgcn_exp2f(acc[ft][r]);
                ksum[ft] += kp;
                ctx[ft]  += kp * vraw[it][r][ft];
            }
        }
    }

#pragma unroll
    for (int ft = 0; ft < 4; ++ft) {
        ksum[ft] += __shfl_xor(ksum[ft], 16); ksum[ft] += __shfl_xor(ksum[ft], 32);
        ctx[ft]  += __shfl_xor(ctx[ft], 16);  ctx[ft]  += __shfl_xor(ctx[ft], 32);
    }

    __shared__ float red[4][128];
    if (lane < 16) {
#pragma unroll
        for (int ft = 0; ft < 4; ++ft) {
            red[w][fp * 4 + ft]      = ksum[ft];
            red[w][64 + fp * 4 + ft] = ctx[ft];
        }
    }
    __syncthreads();
    if (tid < 128) {
        float s = red[0][tid] + red[1][tid] + red[2][tid] + red[3][tid];
        atomicAdd(ws + head * 128 + tid, s);
    }
}

__global__ __launch_bounds__(256, 4) void fa_pass2(const float* __restrict__ Q,
                                                   const float* __restrict__ ws,
                                                   float* __restrict__ out) {
    const int head = blockIdx.x >> 6;   // 32 heads x 64 segments of 64 rows
    const int seg  = blockIdx.x & 63;
    const int tid  = threadIdx.x;
    const int w    = tid >> 6;
    const int lane = tid & 63;
    const int fp   = lane & 15;
    const int g    = lane >> 4;
    const long hbase = (long)head * SEQ;
    const int row0 = seg * 64 + w * 16;

    // ---- issue the HBM Q loads FIRST (only long-latency loads here)
    const float* ap = Q + (hbase + row0 + fp) * DDIM;
    floatx4 qraw[4];
    qraw[0] = *(const floatx4*)(ap + g * 8);
    qraw[1] = *(const floatx4*)(ap + g * 8 + 4);
    qraw[2] = *(const floatx4*)(ap + 32 + g * 8);
    qraw[3] = *(const floatx4*)(ap + 32 + g * 8 + 4);

    // L2-hot: fragment table + per-head stats
    const short* pbf = (const short*)(ws + ACC_FLOATS);
    short8 bfrag[4][2];
    load_bfrag_ws(pbf, lane, bfrag);

    floatx4 ksr  = *(const floatx4*)(ws + head * 128 + fp * 4);
    floatx4 ctxr = *(const floatx4*)(ws + head * 128 + 64 + fp * 4);
#pragma unroll
    for (int ft = 0; ft < 4; ++ft) ksr[ft] += 1e-6f;

    short8 afrag0 = cvt8(qraw[0], qraw[1]);
    short8 afrag1 = cvt8(qraw[2], qraw[3]);

    float qp[4][4];
    float denom[4] = {0.f, 0.f, 0.f, 0.f};
#pragma unroll
    for (int ft = 0; ft < 4; ++ft) {
        floatx4 z = {0.f, 0.f, 0.f, 0.f};
        z = __builtin_amdgcn_mfma_f32_16x16x32_bf16(afrag0, bfrag[ft][0], z, 0, 0, 0);
        z = __builtin_amdgcn_mfma_f32_16x16x32_bf16(afrag1, bfrag[ft][1], z, 0, 0, 0);
#pragma unroll
        for (int r = 0; r < 4; ++r) {
            float e = __builtin_amdgcn_exp2f(z[r]);
            qp[ft][r] = e;
            denom[r] += e * ksr[ft];
        }
    }

#pragma unroll
    for (int r = 0; r < 4; ++r) {
        denom[r] += __shfl_xor(denom[r], 1);
        denom[r] += __shfl_xor(denom[r], 2);
        denom[r] += __shfl_xor(denom[r], 4);
        denom[r] += __shfl_xor(denom[r], 8);
        denom[r] = 1.0f / denom[r];
    }

#pragma unroll
    for (int r = 0; r < 4; ++r) {
        floatx4 o;
#pragma unroll
        for (int ft = 0; ft < 4; ++ft)
            o[ft] = qp[ft][r] * ctxr[ft] * denom[r];
        *(floatx4*)(out + (hbase + row0 + g * 4 + r) * DDIM + fp * 4) = o;
    }
}

extern "C" void kernel_launch(void* const* d_in, const int* in_sizes, int n_in,
                              void* d_out, int out_size, void* d_ws, size_t ws_size,
                              hipStream_t stream) {
    const float* q    = (const float*)d_in[0];
    const float* k    = (const float*)d_in[1];
    const float* v    = (const float*)d_in[2];
    const float* proj = (const float*)d_in[3];
    float* out = (float*)d_out;
    float* ws  = (float*)d_ws;

    fa_prep<<<33, 128, 0, stream>>>(proj, ws);
    fa_pass1<<<NHEADS * 32, 256, 0, stream>>>(k, v, ws);
    fa_pass2<<<NHEADS * 64, 256, 0, stream>>>(q, ws, out);
}